// Round 14
// baseline (792.869 us; speedup 1.0000x reference)
//
#include <hip/hip_runtime.h>
#include <hip/hip_bf16.h>
#include <math.h>

// Problem constants
#define B_  8192
#define IN_ 768
#define D_  128
#define K_  8192
#define L_  3

typedef __attribute__((ext_vector_type(8))) short bf16x8;
typedef __attribute__((ext_vector_type(4))) float f32x4;

// ---------------------------------------------------------------------------
// Fragment-major swizzled layout for a [R][C] matrix (R%16==0, C%32==0):
//   off(row,k) = ((row>>4)*(C/32) + (k>>5))*512 + ((k>>3)&3)*128 + (row&15)*8 + (k&7)
// MFMA fragment load (row-tile rt, k-slice s) for lane l is then
//   plane + ((rt*(C/32)+s)<<9) + l*8   -> fully coalesced 16B/lane (bf16).
// Fragments are contiguous 1 KB chunks -> ideal for global_load_lds staging.
// ---------------------------------------------------------------------------
__device__ __forceinline__ size_t swz(int row, int col, int C)
{
    return ((size_t)((row >> 4) * (C >> 5) + (col >> 5)) << 9)
         + (((col >> 3) & 3) << 7) + ((row & 15) << 3) + (col & 7);
}

// Split f into hi (bf16 RNE) + lo (bf16 RNE of remainder). ~2^-18 rel error.
__device__ __forceinline__ void split2(float f, unsigned short& h, unsigned short& l)
{
    unsigned u = __float_as_uint(f);
    unsigned hb = (u + 0x7FFFu + ((u >> 16) & 1u)) & 0xFFFF0000u;
    h = (unsigned short)(hb >> 16);
    float r = f - __uint_as_float(hb);
    unsigned v = __float_as_uint(r);
    l = (unsigned short)((v + 0x7FFFu + ((v >> 16) & 1u)) >> 16);
}

// Triple split: f = h + m + l, covers all 24 fp32 mantissa bits (~2^-27).
__device__ __forceinline__ void split3(float f, unsigned short& h,
                                       unsigned short& m, unsigned short& l)
{
    unsigned u = __float_as_uint(f);
    unsigned hb = (u + 0x7FFFu + ((u >> 16) & 1u)) & 0xFFFF0000u;
    h = (unsigned short)(hb >> 16);
    float r1 = f - __uint_as_float(hb);
    unsigned v = __float_as_uint(r1);
    unsigned mb = (v + 0x7FFFu + ((v >> 16) & 1u)) & 0xFFFF0000u;
    m = (unsigned short)(mb >> 16);
    float r2 = r1 - __uint_as_float(mb);
    unsigned w = __float_as_uint(r2);
    l = (unsigned short)((w + 0x7FFFu + ((w >> 16) & 1u)) >> 16);
}

__device__ __forceinline__ unsigned short bf16_rne(float f)
{
    unsigned u = __float_as_uint(f);
    return (unsigned short)((u + 0x7FFFu + ((u >> 16) & 1u)) >> 16);
}

// ---------------------------------------------------------------------------
// fp32 [R][C] linear -> swizzled permutation (pure layout; values identical).
// ---------------------------------------------------------------------------
template<int C>
__global__ __launch_bounds__(256)
void swzf32_kernel(const float* __restrict__ src, float* __restrict__ dst)
{
    const int i = blockIdx.x * 256 + threadIdx.x;
    const int row = i / (C / 8);
    const int col = (i - row * (C / 8)) * 8;
    float4 a = *(const float4*)&src[(size_t)row * C + col];
    float4 b = *(const float4*)&src[(size_t)row * C + col + 4];
    const size_t o = swz(row, col, C);
    *(float4*)&dst[o] = a;
    *(float4*)&dst[o + 4] = b;
}

// ---------------------------------------------------------------------------
// Fused weight prep: all 6 weight matrices -> swizzled bf16 planes in ONE
// dispatch. dec weights: split2 (2 planes); enc weights: split3 (3 planes).
// ---------------------------------------------------------------------------
__global__ __launch_bounds__(256)
void prep_weights_kernel(const float* __restrict__ dw1, const float* __restrict__ dw2,
                         const float* __restrict__ dw3, const float* __restrict__ ew1,
                         const float* __restrict__ ew2, const float* __restrict__ ew3,
                         unsigned short* __restrict__ dw1h, unsigned short* __restrict__ dw1l,
                         unsigned short* __restrict__ dw2h, unsigned short* __restrict__ dw2l,
                         unsigned short* __restrict__ dw3h, unsigned short* __restrict__ dw3l,
                         unsigned short* __restrict__ e1h, unsigned short* __restrict__ e1m,
                         unsigned short* __restrict__ e1l,
                         unsigned short* __restrict__ e2h, unsigned short* __restrict__ e2m,
                         unsigned short* __restrict__ e2l,
                         unsigned short* __restrict__ e3h, unsigned short* __restrict__ e3m,
                         unsigned short* __restrict__ e3l)
{
    const int b = blockIdx.x;
    const float* src;
    unsigned short *H, *M = nullptr, *L;
    int kc, idx0;
    bool three;
    if (b < 128)       { src = dw1; H = dw1h; L = dw1l; kc = 128; three = false; idx0 = b * 256; }
    else if (b < 640)  { src = dw2; H = dw2h; L = dw2l; kc = 256; three = false; idx0 = (b - 128) * 256; }
    else if (b < 2176) { src = dw3; H = dw3h; L = dw3l; kc = 512; three = false; idx0 = (b - 640) * 256; }
    else if (b < 3712) { src = ew1; H = e1h; M = e1m; L = e1l; kc = 768; three = true; idx0 = (b - 2176) * 256; }
    else if (b < 4224) { src = ew2; H = e2h; M = e2m; L = e2l; kc = 512; three = true; idx0 = (b - 3712) * 256; }
    else               { src = ew3; H = e3h; M = e3m; L = e3l; kc = 256; three = true; idx0 = (b - 4224) * 256; }

    const int idx = idx0 + threadIdx.x;
    const int row = idx / kc, col = idx - row * kc;
    const size_t o = swz(row, col, kc);
    const float f = src[idx];
    if (three) {
        unsigned short h, m, l;
        split3(f, h, m, l);
        H[o] = h; M[o] = m; L[o] = l;
    } else {
        unsigned short h, l;
        split2(f, h, l);
        H[o] = h; L[o] = l;
    }
}

// ---------------------------------------------------------------------------
// Encoder MFMA GEMM, fp32-faithful: C = act(A @ W^T + bias).
// A fp32 (linear if ASWZ=0, swizzled if 1), triple-split in-register; W in 3
// swizzled bf16 planes. 6 MFMA passes -> ~1e-6 rel error (argmin-id safe).
// Geometry templated: 4 waves x MT m-tiles (BM=64*MT), NT n-tiles (BN=16*NT).
// LESSONS: r11 — grids must stay >=512 blocks (2 blocks/CU) for latency
// hiding; r12 — raising the B-load:MFMA ratio (NT>4 at MT=1) loses more than
// the A-traffic saving. MT=2/NT=4 is the proven optimum.
// ACT: 0=none, 1=silu. CSWZ: fp32 out linear(0)/swizzled(1).
// OUT2: additionally write split2 bf16 planes (swz) of the output (enc3).
// ---------------------------------------------------------------------------
template<int N, int K, int ACT, int ASWZ, int CSWZ, int OUT2, int MT, int NT>
__global__ __launch_bounds__(256)
void mfma_enc_kernel(const float* __restrict__ A,
                     const unsigned short* __restrict__ Wh,
                     const unsigned short* __restrict__ Wm,
                     const unsigned short* __restrict__ Wl,
                     const float* __restrict__ bias, float* __restrict__ C,
                     unsigned short* __restrict__ Rh,
                     unsigned short* __restrict__ Rl)
{
    const int tid  = threadIdx.x;
    const int lane = tid & 63;
    const int w    = tid >> 6;
    const int ln   = lane & 15;
    const int grp  = lane >> 4;
    const int m0   = blockIdx.y * (64 * MT) + w * (16 * MT);
    const int n0   = blockIdx.x * (16 * NT);

    f32x4 acc[MT][NT] = {};

    for (int ks = 0; ks < K; ks += 32) {
        const int s = ks >> 5;
        bf16x8 ah[MT], am[MT], al[MT];
        #pragma unroll
        for (int mt = 0; mt < MT; ++mt) {
            float4 f0, f1;
            if (ASWZ) {
                const size_t base =
                    ((size_t)(((m0 >> 4) + mt) * (K >> 5) + s) << 9) + lane * 8;
                f0 = *(const float4*)&A[base];
                f1 = *(const float4*)&A[base + 4];
            } else {
                const size_t off = (size_t)(m0 + mt * 16 + ln) * K + ks + grp * 8;
                f0 = *(const float4*)&A[off];
                f1 = *(const float4*)&A[off + 4];
            }
            float fv[8] = {f0.x, f0.y, f0.z, f0.w, f1.x, f1.y, f1.z, f1.w};
            #pragma unroll
            for (int e = 0; e < 8; ++e) {
                unsigned short hh, mm, ll;
                split3(fv[e], hh, mm, ll);
                ah[mt][e] = (short)hh;
                am[mt][e] = (short)mm;
                al[mt][e] = (short)ll;
            }
        }
        #pragma unroll
        for (int nt = 0; nt < NT; ++nt) {
            const size_t off =
                ((size_t)(((n0 >> 4) + nt) * (K >> 5) + s) << 9) + lane * 8;
            bf16x8 bh = *(const bf16x8*)&Wh[off];
            bf16x8 bm = *(const bf16x8*)&Wm[off];
            bf16x8 bl = *(const bf16x8*)&Wl[off];
            #pragma unroll
            for (int mt = 0; mt < MT; ++mt) {
                acc[mt][nt] = __builtin_amdgcn_mfma_f32_16x16x32_bf16(ah[mt], bh, acc[mt][nt], 0, 0, 0);
                acc[mt][nt] = __builtin_amdgcn_mfma_f32_16x16x32_bf16(am[mt], bh, acc[mt][nt], 0, 0, 0);
                acc[mt][nt] = __builtin_amdgcn_mfma_f32_16x16x32_bf16(ah[mt], bm, acc[mt][nt], 0, 0, 0);
                acc[mt][nt] = __builtin_amdgcn_mfma_f32_16x16x32_bf16(al[mt], bh, acc[mt][nt], 0, 0, 0);
                acc[mt][nt] = __builtin_amdgcn_mfma_f32_16x16x32_bf16(am[mt], bm, acc[mt][nt], 0, 0, 0);
                acc[mt][nt] = __builtin_amdgcn_mfma_f32_16x16x32_bf16(ah[mt], bl, acc[mt][nt], 0, 0, 0);
            }
        }
    }

    #pragma unroll
    for (int nt = 0; nt < NT; ++nt) {
        const int col = n0 + nt * 16 + ln;
        const float bv = bias[col];
        #pragma unroll
        for (int mt = 0; mt < MT; ++mt) {
            #pragma unroll
            for (int r = 0; r < 4; ++r) {
                const int row = m0 + mt * 16 + grp * 4 + r;
                float v = acc[mt][nt][r] + bv;
                if (ACT == 1) v = v / (1.0f + expf(-v));
                if (CSWZ) C[swz(row, col, N)] = v;
                else      C[(size_t)row * N + col] = v;
                if (OUT2) {
                    unsigned short h, l;
                    split2(v, h, l);
                    const size_t o = swz(row, col, N);
                    Rh[o] = h;
                    Rl[o] = l;
                }
            }
        }
    }
}

// ---------------------------------------------------------------------------
// Split-precision MFMA GEMM (decoder): A,W as swizzled bf16 hi/lo planes;
// dot = hh + lh + hl (~2^-17 rel, only affects recon/loss, ~2% tolerance).
// Geometry templated (BM=64*MT, BN=16*NT). ACT: 1=silu, 2=sigmoid.
// OUT: 0=swizzled bf16 hi/lo pair, 1=linear single bf16.
// ---------------------------------------------------------------------------
template<int N, int K, int ACT, int OUT, int MT, int NT>
__global__ __launch_bounds__(256)
void mfma_gemm_kernel(const unsigned short* __restrict__ A_hi,
                      const unsigned short* __restrict__ A_lo,
                      const unsigned short* __restrict__ W_hi,
                      const unsigned short* __restrict__ W_lo,
                      const float* __restrict__ bias,
                      unsigned short* __restrict__ C_hi,
                      unsigned short* __restrict__ C_lo)
{
    const int tid  = threadIdx.x;
    const int lane = tid & 63;
    const int w    = tid >> 6;
    const int ln   = lane & 15;
    const int grp  = lane >> 4;
    const int m0   = blockIdx.y * (64 * MT) + w * (16 * MT);
    const int n0   = blockIdx.x * (16 * NT);

    f32x4 acc[MT][NT] = {};

    for (int ks = 0; ks < K; ks += 32) {
        const int s = ks >> 5;
        bf16x8 ah[MT], al[MT];
        #pragma unroll
        for (int mt = 0; mt < MT; ++mt) {
            const size_t off =
                ((size_t)(((m0 >> 4) + mt) * (K >> 5) + s) << 9) + lane * 8;
            ah[mt] = *(const bf16x8*)&A_hi[off];
            al[mt] = *(const bf16x8*)&A_lo[off];
        }
        #pragma unroll
        for (int nt = 0; nt < NT; ++nt) {
            const size_t off =
                ((size_t)(((n0 >> 4) + nt) * (K >> 5) + s) << 9) + lane * 8;
            bf16x8 bh = *(const bf16x8*)&W_hi[off];
            bf16x8 bl = *(const bf16x8*)&W_lo[off];
            #pragma unroll
            for (int mt = 0; mt < MT; ++mt) {
                acc[mt][nt] = __builtin_amdgcn_mfma_f32_16x16x32_bf16(ah[mt], bh, acc[mt][nt], 0, 0, 0);
                acc[mt][nt] = __builtin_amdgcn_mfma_f32_16x16x32_bf16(al[mt], bh, acc[mt][nt], 0, 0, 0);
                acc[mt][nt] = __builtin_amdgcn_mfma_f32_16x16x32_bf16(ah[mt], bl, acc[mt][nt], 0, 0, 0);
            }
        }
    }

    #pragma unroll
    for (int nt = 0; nt < NT; ++nt) {
        const int col = n0 + nt * 16 + ln;
        const float bv = bias[col];
        #pragma unroll
        for (int mt = 0; mt < MT; ++mt) {
            #pragma unroll
            for (int r = 0; r < 4; ++r) {
                const int row = m0 + mt * 16 + grp * 4 + r;
                float v = acc[mt][nt][r] + bv;
                if (ACT == 1) v = v / (1.0f + expf(-v));
                if (ACT == 2) v = 1.0f / (1.0f + expf(-v));
                if (OUT == 0) {
                    unsigned short h, l;
                    split2(v, h, l);
                    const size_t o = swz(row, col, N);
                    C_hi[o] = h;
                    C_lo[o] = l;
                } else {
                    C_hi[(size_t)row * N + col] = bf16_rne(v);
                }
            }
        }
    }
}

// ---------------------------------------------------------------------------
// Per-row L2 normalize + recon partial.
// ---------------------------------------------------------------------------
__global__ __launch_bounds__(256)
void norm_recon_kernel(const unsigned short* __restrict__ xhat,
                       const float* __restrict__ x,
                       float* __restrict__ recon_row)
{
    const int b = blockIdx.x;
    const int tid = threadIdx.x;
    __shared__ float ws[4];
    __shared__ float nrm_s;

    float v[3];
    float ss = 0.0f;
    #pragma unroll
    for (int c = 0; c < 3; ++c) {
        unsigned short u = xhat[(size_t)b * 768 + tid + c * 256];
        v[c] = __uint_as_float((unsigned)u << 16);
        ss += v[c] * v[c];
    }
    for (int off = 32; off > 0; off >>= 1) ss += __shfl_down(ss, off, 64);
    if ((tid & 63) == 0) ws[tid >> 6] = ss;
    __syncthreads();
    if (tid == 0) nrm_s = fmaxf(sqrtf(ws[0] + ws[1] + ws[2] + ws[3]), 1e-12f);
    __syncthreads();
    const float inv = 1.0f / nrm_s;
    float ra = 0.0f;
    #pragma unroll
    for (int c = 0; c < 3; ++c) {
        float dx = v[c] * inv - x[(size_t)b * 768 + tid + c * 256];
        ra += dx * dx;
    }
    for (int off = 32; off > 0; off >>= 1) ra += __shfl_down(ra, off, 64);
    if ((tid & 63) == 0) ws[tid >> 6] = ra;
    __syncthreads();
    if (tid == 0) recon_row[b] = ws[0] + ws[1] + ws[2] + ws[3];
}

// ---------------------------------------------------------------------------
// Projected codebook: cbp fp32 linear + swizzled bf16 hi/lo planes + norms.
// ---------------------------------------------------------------------------
__global__ __launch_bounds__(128)
void proj_split_kernel(const float* __restrict__ cbl, const float* __restrict__ projl,
                       float* __restrict__ cbp, unsigned short* __restrict__ cbp_hi,
                       unsigned short* __restrict__ cbp_lo, float* __restrict__ cbn)
{
    __shared__ float cbs[8][128];
    __shared__ float wsum[8][2];
    const int tid = threadIdx.x;          // = d
    const int k0 = blockIdx.x * 8;

    #pragma unroll
    for (int i = 0; i < 2; ++i) {
        int idx4 = tid + i * 128;
        int r = idx4 >> 5, c4 = (idx4 & 31) * 4;
        *(float4*)&cbs[r][c4] = *(const float4*)&cbl[(size_t)(k0 + r) * 128 + c4];
    }
    __syncthreads();

    float acc[8] = {};
    for (int j4 = 0; j4 < 32; ++j4) {
        float4 pv = *(const float4*)&projl[(size_t)tid * 128 + j4 * 4];
        #pragma unroll
        for (int r = 0; r < 8; ++r) {
            float4 cv = *(float4*)&cbs[r][j4 * 4];
            acc[r] += pv.x * cv.x + pv.y * cv.y + pv.z * cv.z + pv.w * cv.w;
        }
    }
    #pragma unroll
    for (int r = 0; r < 8; ++r) {
        cbp[(size_t)(k0 + r) * 128 + tid] = acc[r];
        unsigned short h, l;
        split2(acc[r], h, l);
        const size_t o = swz(k0 + r, tid, 128);
        cbp_hi[o] = h;
        cbp_lo[o] = l;
        float v = acc[r] * acc[r];
        #pragma unroll
        for (int off = 32; off > 0; off >>= 1) v += __shfl_down(v, off, 64);
        if ((tid & 63) == 0) wsum[r][tid >> 6] = v;
    }
    __syncthreads();
    if (tid < 8) cbn[k0 + tid] = wsum[tid][0] + wsum[tid][1];
}

// ---------------------------------------------------------------------------
// MFMA distance argmin (swizzled planes; ids bit-identical to numpy).
// BM=256 (4 m-tiles/wave), 32-col tiles x 8 its, double-buffered 2x16KB LDS
// staged via global_load_lds. r14: launch_bounds min-waves 2 -> 4 (4 blocks/
// CU co-resident; LDS 128KB of 160, VGPR 112 < 128 so 16 waves/CU legal) to
// overlap one block's LDS/VALU phases with another's MFMA phase.
// ---------------------------------------------------------------------------
__device__ __forceinline__ unsigned int fkey(float s) {
    unsigned int u = __float_as_uint(s);
    return (u & 0x80000000u) ? ~u : (u | 0x80000000u);
}

__global__ __launch_bounds__(256, 4)
void argmin_mfma_kernel(const unsigned short* __restrict__ res_hi,
                        const unsigned short* __restrict__ res_lo,
                        const unsigned short* __restrict__ cbp_hi,
                        const unsigned short* __restrict__ cbp_lo,
                        const float* __restrict__ cbn,
                        unsigned long long* __restrict__ minkey)
{
    __shared__ unsigned short lds[16384];   // 2 buffers x 16 KB
    const int tid  = threadIdx.x;
    const int lane = tid & 63;
    const int w    = tid >> 6;
    const int ln   = lane & 15;
    const int grp  = lane >> 4;
    const int m0   = blockIdx.y * 256 + w * 64;
    const int c0b  = blockIdx.x * 256;

    // A fragments: 64 rows/wave (4 m-tiles), held in registers (~128 VGPR)
    bf16x8 a_hi[4][4], a_lo[4][4];
    #pragma unroll
    for (int mt = 0; mt < 4; ++mt) {
        #pragma unroll
        for (int s = 0; s < 4; ++s) {
            const size_t off =
                ((size_t)(((m0 >> 4) + mt) * 4 + s) << 9) + lane * 8;
            a_hi[mt][s] = *(const bf16x8*)&res_hi[off];
            a_lo[mt][s] = *(const bf16x8*)&res_lo[off];
        }
    }

    // Per it: B tile = 32 cols x 128 k x 2 planes = 16 KB = 16 frags of 1KB.
    const unsigned short* splane = (w < 2) ? cbp_hi : cbp_lo;
    const unsigned lbase = (unsigned)((w >> 1) * 8192 + (w & 1) * 4096); // bytes

    auto STAGE = [&](int buf, int it) {
        const size_t g0 = ((size_t)(c0b >> 4) * 4 + it * 8 + (w & 1) * 4) * 512
                        + lane * 8;                           // shorts
        const unsigned l0 = (unsigned)buf * 16384u + lbase;   // bytes
        #pragma unroll
        for (int i = 0; i < 4; ++i) {
            __builtin_amdgcn_global_load_lds(
                (const __attribute__((address_space(1))) unsigned int*)(splane + g0 + i * 512),
                (__attribute__((address_space(3))) unsigned int*)((char*)lds + l0 + i * 1024),
                16, 0, 0);
        }
    };

    float best_s[4][4];
    int   best_c[4][4];
    #pragma unroll
    for (int mt = 0; mt < 4; ++mt)
        #pragma unroll
        for (int r = 0; r < 4; ++r) { best_s[mt][r] = 3.4e38f; best_c[mt][r] = 0; }

    STAGE(0, 0);
    __syncthreads();                        // drains vmcnt -> buf0 ready

    for (int it = 0; it < 8; ++it) {
        const int buf = it & 1;
        if (it < 7) STAGE(buf ^ 1, it + 1); // async prefetch into other buffer
        const unsigned short* lb = lds + buf * 8192;   // shorts
        const int c0 = c0b + it * 32;
        f32x4 acc[4][2] = {};
        #pragma unroll
        for (int s = 0; s < 4; ++s) {
            #pragma unroll
            for (int t = 0; t < 2; ++t) {
                const int fo = (t * 4 + s) * 512 + lane * 8;
                bf16x8 bh = *(const bf16x8*)&lb[fo];
                bf16x8 bl = *(const bf16x8*)&lb[fo + 4096];
                #pragma unroll
                for (int mt = 0; mt < 4; ++mt) {
                    acc[mt][t] = __builtin_amdgcn_mfma_f32_16x16x32_bf16(a_hi[mt][s], bh, acc[mt][t], 0, 0, 0);
                    acc[mt][t] = __builtin_amdgcn_mfma_f32_16x16x32_bf16(a_lo[mt][s], bh, acc[mt][t], 0, 0, 0);
                    acc[mt][t] = __builtin_amdgcn_mfma_f32_16x16x32_bf16(a_hi[mt][s], bl, acc[mt][t], 0, 0, 0);
                }
            }
        }
        #pragma unroll
        for (int t = 0; t < 2; ++t) {
            const int col = c0 + t * 16 + ln;
            const float cn = cbn[col];
            #pragma unroll
            for (int mt = 0; mt < 4; ++mt)
                #pragma unroll
                for (int r = 0; r < 4; ++r) {
                    float sc = fmaf(-2.0f, acc[mt][t][r], cn);
                    if (sc < best_s[mt][r]) {   // strict <: first col wins ties
                        best_s[mt][r] = sc;
                        best_c[mt][r] = col;
                    }
                }
        }
        if (it < 7) __syncthreads();        // next buf ready, cur buf free
    }

    #pragma unroll
    for (int mt = 0; mt < 4; ++mt)
        #pragma unroll
        for (int r = 0; r < 4; ++r) {
            unsigned long long b =
                ((unsigned long long)fkey(best_s[mt][r]) << 32)
                | (unsigned int)best_c[mt][r];
            #pragma unroll
            for (int off = 1; off < 16; off <<= 1) {
                unsigned lo32 = (unsigned)b, hi32 = (unsigned)(b >> 32);
                lo32 = __shfl_xor(lo32, off);
                hi32 = __shfl_xor(hi32, off);
                unsigned long long o = ((unsigned long long)hi32 << 32) | lo32;
                if (o < b) b = o;
            }
            if (ln == 0) atomicMin(&minkey[m0 + mt * 16 + grp * 4 + r], b);
        }
}

// ---------------------------------------------------------------------------
// Per-layer epilogue. layer==0 WRITES qloss/z (no memset needed); layer 2
// also emits z planes for the decoder.
// ---------------------------------------------------------------------------
__global__ __launch_bounds__(128)
void finalize_kernel(float* __restrict__ res, const float* __restrict__ cbp,
                     const unsigned long long* __restrict__ minkey,
                     float* __restrict__ qloss, float* __restrict__ z,
                     int* __restrict__ ids, float* __restrict__ embs_norm_out,
                     unsigned long long* __restrict__ keys,
                     unsigned short* __restrict__ res_hi,
                     unsigned short* __restrict__ res_lo,
                     unsigned short* __restrict__ z_hi,
                     unsigned short* __restrict__ z_lo, int layer)
{
    const int b = blockIdx.x;
    const int tid = threadIdx.x;
    const int id = (int)(minkey[b] & 0xFFFFFFFFull);
    float e = cbp[(size_t)id * 128 + tid];
    float r = res[(size_t)b * 128 + tid];
    float d = r - e;
    float v1 = d * d, v2 = e * e;
    for (int off = 32; off > 0; off >>= 1) {
        v1 += __shfl_down(v1, off, 64);
        v2 += __shfl_down(v2, off, 64);
    }
    __shared__ float ws[4];
    if ((tid & 63) == 0) { ws[(tid >> 6) * 2] = v1; ws[(tid >> 6) * 2 + 1] = v2; }
    __syncthreads();
    if (tid == 0) {
        float d2 = ws[0] + ws[2];
        float n2 = ws[1] + ws[3];
        float prev = (layer == 0) ? 0.0f : qloss[b];
        qloss[b] = prev + 1.25f * d2;           // emb_loss + 0.25*query_loss
        embs_norm_out[b * 3 + layer] = sqrtf(n2);
        ids[b * 3 + layer] = id;
        if (layer == 2) {
            keys[b] = (unsigned long long)ids[b * 3 + 0]
                    | ((unsigned long long)ids[b * 3 + 1] << 13)
                    | ((unsigned long long)id << 26);
        }
    }
    float zprev = (layer == 0) ? 0.0f : z[(size_t)b * 128 + tid];
    float nz = zprev + e;
    z[(size_t)b * 128 + tid] = nz;
    const size_t o = swz(b, tid, 128);
    if (layer == 2) {
        unsigned short zh, zl;
        split2(nz, zh, zl);
        z_hi[o] = zh;
        z_lo[o] = zl;
    }
    float nr = r - e;
    res[(size_t)b * 128 + tid] = nr;
    unsigned short h, l;
    split2(nr, h, l);
    res_hi[o] = h;
    res_lo[o] = l;
}

// ---------------------------------------------------------------------------
// Distinct-triple count: wave match-any dedup (leaders only touch the global
// table) then per-wave aggregated count. Deterministic.
// ---------------------------------------------------------------------------
__global__ __launch_bounds__(256)
void uniq_hash_kernel(const unsigned long long* __restrict__ keys,
                      unsigned long long* __restrict__ table,
                      int* __restrict__ count)
{
    const int i = blockIdx.x * 256 + threadIdx.x;
    const int lane = threadIdx.x & 63;
    const unsigned long long k = keys[i];

    // wave match-any: elect one leader lane per distinct key
    bool resolved = false, leader = false;
    while (true) {
        unsigned long long unres = __ballot(!resolved);
        if (unres == 0) break;
        const int src = (int)(__ffsll((long long)unres) - 1);
        unsigned slo = __shfl((unsigned)k, src);
        unsigned shi = __shfl((unsigned)(k >> 32), src);
        unsigned long long kk = ((unsigned long long)shi << 32) | slo;
        if (!resolved && k == kk) {
            resolved = true;
            leader = (lane == src);
        }
    }

    bool ins = false;
    if (leader) {
        unsigned h = (unsigned)((k * 0x9E3779B97F4A7C15ull) >> 50);   // 14 bits
        while (true) {
            unsigned long long old = atomicCAS(&table[h], ~0ULL, k);
            if (old == ~0ULL) { ins = true; break; }        // first insert
            if (old == k) break;                            // duplicate
            h = (h + 1) & 16383;
        }
    }
    unsigned long long m = __ballot(ins);
    if (lane == 0 && m) atomicAdd(count, (int)__popcll(m));
}

// ---------------------------------------------------------------------------
// Final scalars.
// ---------------------------------------------------------------------------
__global__ __launch_bounds__(256)
void scalars_kernel(const float* __restrict__ qloss,
                    const float* __restrict__ recon_row,
                    const int* __restrict__ count, float* __restrict__ out)
{
    const int tid = threadIdx.x;
    float qs = 0.0f, rs = 0.0f;
    for (int i = tid; i < 8192; i += 256) qs += qloss[i];
    for (int i = tid; i < 8192; i += 256) rs += recon_row[i];
    for (int off = 32; off > 0; off >>= 1) {
        qs += __shfl_down(qs, off, 64);
        rs += __shfl_down(rs, off, 64);
    }
    __shared__ float w[8];
    if ((tid & 63) == 0) { w[(tid >> 6) * 2] = qs; w[(tid >> 6) * 2 + 1] = rs; }
    __syncthreads();
    if (tid == 0) {
        float qsum = w[0] + w[2] + w[4] + w[6];
        float rsum = w[1] + w[3] + w[5] + w[7];
        float qmean = qsum / 8192.0f;
        out[0] = rsum + qmean;        // loss = (recon + qloss).mean()
        out[1] = rsum;                // recon
        out[2] = qmean;               // qloss.mean()
        out[24579] = (float)(*count) / 8192.0f;   // p_unique
    }
}

// ---------------------------------------------------------------------------
extern "C" void kernel_launch(void* const* d_in, const int* in_sizes, int n_in,
                              void* d_out, int out_size, void* d_ws, size_t ws_size,
                              hipStream_t stream)
{
    const float* x      = (const float*)d_in[0];
    const float* enc_w1 = (const float*)d_in[1];
    const float* enc_b1 = (const float*)d_in[2];
    const float* enc_w2 = (const float*)d_in[3];
    const float* enc_b2 = (const float*)d_in[4];
    const float* enc_w3 = (const float*)d_in[5];
    const float* enc_b3 = (const float*)d_in[6];
    const float* dec_w1 = (const float*)d_in[7];
    const float* dec_b1 = (const float*)d_in[8];
    const float* dec_w2 = (const float*)d_in[9];
    const float* dec_b2 = (const float*)d_in[10];
    const float* dec_w3 = (const float*)d_in[11];
    const float* dec_b3 = (const float*)d_in[12];
    const float* codebooks = (const float*)d_in[13];
    const float* projs     = (const float*)d_in[14];
    float* out = (float*)d_out;

    char* ws = (char*)d_ws;
    const size_t MB = 1024 * 1024;

    // --- region [0, 16M): encoder h1 f32 (swz) ; decoder g2_hi/g2_lo (swz)
    float* h1 = (float*)ws;                                        // 8192x512 f32
    unsigned short* g2_hi = (unsigned short*)ws;                   // 8192x512 bf16
    unsigned short* g2_lo = (unsigned short*)(ws + 8 * MB);
    // --- region [16M, 24M): encoder h2 f32 (swz) ; quant splits ; dec g1 (swz)
    float* h2 = (float*)(ws + 16 * MB);                            // 8192x256 f32
    unsigned short* res_hi = (unsigned short*)(ws + 16 * MB);      // 8192x128
    unsigned short* res_lo = (unsigned short*)(ws + 18 * MB);
    unsigned short* cbp_hi = (unsigned short*)(ws + 20 * MB);
    unsigned short* cbp_lo = (unsigned short*)(ws + 22 * MB);
    unsigned short* g1_hi  = (unsigned short*)(ws + 16 * MB);      // 8192x256 (decoder)
    unsigned short* g1_lo  = (unsigned short*)(ws + 20 * MB);
    // --- region [24M, 28M): res f32 (linear)
    float* res = (float*)(ws + 24 * MB);                           // 8192x128 f32
    // --- region [28M, 32M): cbp f32 (linear) ; decoder z_hi/z_lo (swz)
    float* cbp = (float*)(ws + 28 * MB);                           // 8192x128 f32
    unsigned short* z_hi = (unsigned short*)(ws + 28 * MB);        // 8192x128
    unsigned short* z_lo = (unsigned short*)(ws + 30 * MB);
    // --- region [32M, 36M): z f32 (linear)
    float* z = (float*)(ws + 32 * MB);                             // 8192x128 f32
    // --- region [36M, ...): weight splits (all swz) + small buffers
    char* p = ws + 36 * MB;
    unsigned short* dw1_hi = (unsigned short*)p; p += 256 * 128 * 2;
    unsigned short* dw1_lo = (unsigned short*)p; p += 256 * 128 * 2;
    unsigned short* dw2_hi = (unsigned short*)p; p += 512 * 256 * 2;
    unsigned short* dw2_lo = (unsigned short*)p; p += 512 * 256 * 2;
    unsigned short* dw3_hi = (unsigned short*)p; p += 768 * 512 * 2;
    unsigned short* dw3_lo = (unsigned short*)p; p += 768 * 512 * 2;
    unsigned short* ew1_h  = (unsigned short*)p; p += 512 * 768 * 2;
    unsigned short* ew1_m  = (unsigned short*)p; p += 512 * 768 * 2;
    unsigned short* ew1_l  = (unsigned short*)p; p += 512 * 768 * 2;
    unsigned short* ew2_h  = (unsigned short*)p; p += 256 * 512 * 2;
    unsigned short* ew2_m  = (unsigned short*)p; p += 256 * 512 * 2;
    unsigned short* ew2_l  = (unsigned short*)p; p += 256 * 512 * 2;
    unsigned short* ew3_h  = (unsigned short*)p; p += 128 * 256 * 2;
    unsigned short* ew3_m  = (unsigned short*)p; p += 128 * 256 * 2;
    unsigned short* ew3_l  = (unsigned short*)p; p += 128 * 256 * 2;
    float* cbn       = (float*)p; p += 8192 * 4;
    float* qloss     = (float*)p; p += 8192 * 4;
    float* recon_row = (float*)p; p += 8192 * 4;
    unsigned long long* minkey = (unsigned long long*)p; p += 8192 * 8;
    unsigned long long* keys   = (unsigned long long*)p; p += 8192 * 8;
    unsigned long long* table  = (unsigned long long*)p; p += 16384 * 8;
    int* ids   = (int*)p; p += 8192 * 3 * 4;
    int* count = (int*)p; p += 256;                      // pad to alignment
    unsigned short* xhat = (unsigned short*)p; p += (size_t)8192 * 768 * 2;
    // optional x swizzle buffer (24 MB) — only if workspace is big enough
    float* xs = (float*)p;
    const bool use_xs =
        ((size_t)(p - ws) + (size_t)8192 * 768 * 4) <= ws_size;

    hipMemsetAsync(count, 0, sizeof(int), stream);
    hipMemsetAsync(table, 0xFF, 16384 * sizeof(unsigned long long), stream);

    // all 6 weight splits fused into one dispatch
    prep_weights_kernel<<<4352, 256, 0, stream>>>(
        dec_w1, dec_w2, dec_w3, enc_w1, enc_w2, enc_w3,
        dw1_hi, dw1_lo, dw2_hi, dw2_lo, dw3_hi, dw3_lo,
        ew1_h, ew1_m, ew1_l, ew2_h, ew2_m, ew2_l, ew3_h, ew3_m, ew3_l);

    // encoder (exact-split MFMA, fp32-faithful). Proven r10 geometry
    // throughout: MT=2/NT=4 (BM=128/BN=64) — r11/r12 alternatives regressed.
    if (use_xs) {
        swzf32_kernel<768><<<3072, 256, 0, stream>>>(x, xs);
        mfma_enc_kernel<512, 768, 1, 1, 1, 0, 2, 4><<<dim3(8, 64), 256, 0, stream>>>(
            xs, ew1_h, ew1_m, ew1_l, enc_b1, h1, nullptr, nullptr);
    } else {
        mfma_enc_kernel<512, 768, 1, 0, 1, 0, 2, 4><<<dim3(8, 64), 256, 0, stream>>>(
            x, ew1_h, ew1_m, ew1_l, enc_b1, h1, nullptr, nullptr);
    }
    mfma_enc_kernel<256, 512, 1, 1, 1, 0, 2, 4><<<dim3(4, 64), 256, 0, stream>>>(
        h1, ew2_h, ew2_m, ew2_l, enc_b2, h2, nullptr, nullptr);
    mfma_enc_kernel<128, 256, 0, 1, 0, 1, 2, 4><<<dim3(2, 64), 256, 0, stream>>>(
        h2, ew3_h, ew3_m, ew3_l, enc_b3, res, res_hi, res_lo);

    // residual quantization layers
    for (int l = 0; l < 3; ++l) {
        proj_split_kernel<<<1024, 128, 0, stream>>>(codebooks + (size_t)l * 8192 * 128,
                                                    projs + (size_t)l * 128 * 128,
                                                    cbp, cbp_hi, cbp_lo, cbn);
        hipMemsetAsync(minkey, 0xFF, 8192 * sizeof(unsigned long long), stream);
        argmin_mfma_kernel<<<dim3(32, 32), 256, 0, stream>>>(res_hi, res_lo,
                                                             cbp_hi, cbp_lo, cbn, minkey);
        finalize_kernel<<<8192, 128, 0, stream>>>(res, cbp, minkey, qloss, z,
                                                  ids, out + 3, keys,
                                                  res_hi, res_lo, z_hi, z_lo, l);
    }

    // decoder (split-precision MFMA, swizzled planes; r10-proven geometry)
    mfma_gemm_kernel<256, 128, 1, 0, 2, 8><<<dim3(2, 64), 256, 0, stream>>>(
        z_hi, z_lo, dw1_hi, dw1_lo, dec_b1, g1_hi, g1_lo);
    mfma_gemm_kernel<512, 256, 1, 0, 2, 8><<<dim3(4, 64), 256, 0, stream>>>(
        g1_hi, g1_lo, dw2_hi, dw2_lo, dec_b2, g2_hi, g2_lo);
    mfma_gemm_kernel<768, 512, 2, 1, 2, 8><<<dim3(6, 64), 256, 0, stream>>>(
        g2_hi, g2_lo, dw3_hi, dw3_lo, dec_b3, xhat, nullptr);
    norm_recon_kernel<<<8192, 256, 0, stream>>>(xhat, x, recon_row);

    // diagnostics
    uniq_hash_kernel<<<32, 256, 0, stream>>>(keys, table, count);
    scalars_kernel<<<1, 256, 0, stream>>>(qloss, recon_row, count, out);
}

// Round 16
// 447.959 us; speedup vs baseline: 1.7700x; 1.7700x over previous
//
#include <hip/hip_runtime.h>
#include <hip/hip_bf16.h>
#include <math.h>

// Problem constants
#define B_  8192
#define IN_ 768
#define D_  128
#define K_  8192
#define L_  3

typedef __attribute__((ext_vector_type(8))) short bf16x8;
typedef __attribute__((ext_vector_type(4))) float f32x4;

// ---------------------------------------------------------------------------
// Fragment-major swizzled layout for a [R][C] matrix (R%16==0, C%32==0):
//   off(row,k) = ((row>>4)*(C/32) + (k>>5))*512 + ((k>>3)&3)*128 + (row&15)*8 + (k&7)
// MFMA fragment load (row-tile rt, k-slice s) for lane l is then
//   plane + ((rt*(C/32)+s)<<9) + l*8   -> fully coalesced 16B/lane (bf16).
// Fragments are contiguous 1 KB chunks -> ideal for global_load_lds staging.
// ---------------------------------------------------------------------------
__device__ __forceinline__ size_t swz(int row, int col, int C)
{
    return ((size_t)((row >> 4) * (C >> 5) + (col >> 5)) << 9)
         + (((col >> 3) & 3) << 7) + ((row & 15) << 3) + (col & 7);
}

// Split f into hi (bf16 RNE) + lo (bf16 RNE of remainder). ~2^-18 rel error.
__device__ __forceinline__ void split2(float f, unsigned short& h, unsigned short& l)
{
    unsigned u = __float_as_uint(f);
    unsigned hb = (u + 0x7FFFu + ((u >> 16) & 1u)) & 0xFFFF0000u;
    h = (unsigned short)(hb >> 16);
    float r = f - __uint_as_float(hb);
    unsigned v = __float_as_uint(r);
    l = (unsigned short)((v + 0x7FFFu + ((v >> 16) & 1u)) >> 16);
}

// Triple split: f = h + m + l, covers all 24 fp32 mantissa bits (~2^-27).
__device__ __forceinline__ void split3(float f, unsigned short& h,
                                       unsigned short& m, unsigned short& l)
{
    unsigned u = __float_as_uint(f);
    unsigned hb = (u + 0x7FFFu + ((u >> 16) & 1u)) & 0xFFFF0000u;
    h = (unsigned short)(hb >> 16);
    float r1 = f - __uint_as_float(hb);
    unsigned v = __float_as_uint(r1);
    unsigned mb = (v + 0x7FFFu + ((v >> 16) & 1u)) & 0xFFFF0000u;
    m = (unsigned short)(mb >> 16);
    float r2 = r1 - __uint_as_float(mb);
    unsigned w = __float_as_uint(r2);
    l = (unsigned short)((w + 0x7FFFu + ((w >> 16) & 1u)) >> 16);
}

__device__ __forceinline__ unsigned short bf16_rne(float f)
{
    unsigned u = __float_as_uint(f);
    return (unsigned short)((u + 0x7FFFu + ((u >> 16) & 1u)) >> 16);
}

// ---------------------------------------------------------------------------
// fp32 [R][C] linear -> swizzled permutation (pure layout; values identical).
// ---------------------------------------------------------------------------
template<int C>
__global__ __launch_bounds__(256)
void swzf32_kernel(const float* __restrict__ src, float* __restrict__ dst)
{
    const int i = blockIdx.x * 256 + threadIdx.x;
    const int row = i / (C / 8);
    const int col = (i - row * (C / 8)) * 8;
    float4 a = *(const float4*)&src[(size_t)row * C + col];
    float4 b = *(const float4*)&src[(size_t)row * C + col + 4];
    const size_t o = swz(row, col, C);
    *(float4*)&dst[o] = a;
    *(float4*)&dst[o + 4] = b;
}

// ---------------------------------------------------------------------------
// Fused weight prep: all 6 weight matrices -> swizzled bf16 planes in ONE
// dispatch. dec weights: split2 (2 planes); enc weights: split3 (3 planes).
// ---------------------------------------------------------------------------
__global__ __launch_bounds__(256)
void prep_weights_kernel(const float* __restrict__ dw1, const float* __restrict__ dw2,
                         const float* __restrict__ dw3, const float* __restrict__ ew1,
                         const float* __restrict__ ew2, const float* __restrict__ ew3,
                         unsigned short* __restrict__ dw1h, unsigned short* __restrict__ dw1l,
                         unsigned short* __restrict__ dw2h, unsigned short* __restrict__ dw2l,
                         unsigned short* __restrict__ dw3h, unsigned short* __restrict__ dw3l,
                         unsigned short* __restrict__ e1h, unsigned short* __restrict__ e1m,
                         unsigned short* __restrict__ e1l,
                         unsigned short* __restrict__ e2h, unsigned short* __restrict__ e2m,
                         unsigned short* __restrict__ e2l,
                         unsigned short* __restrict__ e3h, unsigned short* __restrict__ e3m,
                         unsigned short* __restrict__ e3l)
{
    const int b = blockIdx.x;
    const float* src;
    unsigned short *H, *M = nullptr, *L;
    int kc, idx0;
    bool three;
    if (b < 128)       { src = dw1; H = dw1h; L = dw1l; kc = 128; three = false; idx0 = b * 256; }
    else if (b < 640)  { src = dw2; H = dw2h; L = dw2l; kc = 256; three = false; idx0 = (b - 128) * 256; }
    else if (b < 2176) { src = dw3; H = dw3h; L = dw3l; kc = 512; three = false; idx0 = (b - 640) * 256; }
    else if (b < 3712) { src = ew1; H = e1h; M = e1m; L = e1l; kc = 768; three = true; idx0 = (b - 2176) * 256; }
    else if (b < 4224) { src = ew2; H = e2h; M = e2m; L = e2l; kc = 512; three = true; idx0 = (b - 3712) * 256; }
    else               { src = ew3; H = e3h; M = e3m; L = e3l; kc = 256; three = true; idx0 = (b - 4224) * 256; }

    const int idx = idx0 + threadIdx.x;
    const int row = idx / kc, col = idx - row * kc;
    const size_t o = swz(row, col, kc);
    const float f = src[idx];
    if (three) {
        unsigned short h, m, l;
        split3(f, h, m, l);
        H[o] = h; M[o] = m; L[o] = l;
    } else {
        unsigned short h, l;
        split2(f, h, l);
        H[o] = h; L[o] = l;
    }
}

// ---------------------------------------------------------------------------
// Encoder MFMA GEMM, fp32-faithful: C = act(A @ W^T + bias).
// A fp32 (linear if ASWZ=0, swizzled if 1), triple-split in-register; W in 3
// swizzled bf16 planes. 6 MFMA passes -> ~1e-6 rel error (argmin-id safe).
// Geometry templated: 4 waves x MT m-tiles (BM=64*MT), NT n-tiles (BN=16*NT).
// LESSONS: r11 — grids must stay >=512 blocks (2 blocks/CU); r12 — NT>4 at
// MT=1 over-exposes B-load latency. MT=2/NT=4 is the proven optimum.
// ACT: 0=none, 1=silu. CSWZ: fp32 out linear(0)/swizzled(1).
// OUT2: additionally write split2 bf16 planes (swz) of the output (enc3).
// ---------------------------------------------------------------------------
template<int N, int K, int ACT, int ASWZ, int CSWZ, int OUT2, int MT, int NT>
__global__ __launch_bounds__(256)
void mfma_enc_kernel(const float* __restrict__ A,
                     const unsigned short* __restrict__ Wh,
                     const unsigned short* __restrict__ Wm,
                     const unsigned short* __restrict__ Wl,
                     const float* __restrict__ bias, float* __restrict__ C,
                     unsigned short* __restrict__ Rh,
                     unsigned short* __restrict__ Rl)
{
    const int tid  = threadIdx.x;
    const int lane = tid & 63;
    const int w    = tid >> 6;
    const int ln   = lane & 15;
    const int grp  = lane >> 4;
    const int m0   = blockIdx.y * (64 * MT) + w * (16 * MT);
    const int n0   = blockIdx.x * (16 * NT);

    f32x4 acc[MT][NT] = {};

    for (int ks = 0; ks < K; ks += 32) {
        const int s = ks >> 5;
        bf16x8 ah[MT], am[MT], al[MT];
        #pragma unroll
        for (int mt = 0; mt < MT; ++mt) {
            float4 f0, f1;
            if (ASWZ) {
                const size_t base =
                    ((size_t)(((m0 >> 4) + mt) * (K >> 5) + s) << 9) + lane * 8;
                f0 = *(const float4*)&A[base];
                f1 = *(const float4*)&A[base + 4];
            } else {
                const size_t off = (size_t)(m0 + mt * 16 + ln) * K + ks + grp * 8;
                f0 = *(const float4*)&A[off];
                f1 = *(const float4*)&A[off + 4];
            }
            float fv[8] = {f0.x, f0.y, f0.z, f0.w, f1.x, f1.y, f1.z, f1.w};
            #pragma unroll
            for (int e = 0; e < 8; ++e) {
                unsigned short hh, mm, ll;
                split3(fv[e], hh, mm, ll);
                ah[mt][e] = (short)hh;
                am[mt][e] = (short)mm;
                al[mt][e] = (short)ll;
            }
        }
        #pragma unroll
        for (int nt = 0; nt < NT; ++nt) {
            const size_t off =
                ((size_t)(((n0 >> 4) + nt) * (K >> 5) + s) << 9) + lane * 8;
            bf16x8 bh = *(const bf16x8*)&Wh[off];
            bf16x8 bm = *(const bf16x8*)&Wm[off];
            bf16x8 bl = *(const bf16x8*)&Wl[off];
            #pragma unroll
            for (int mt = 0; mt < MT; ++mt) {
                acc[mt][nt] = __builtin_amdgcn_mfma_f32_16x16x32_bf16(ah[mt], bh, acc[mt][nt], 0, 0, 0);
                acc[mt][nt] = __builtin_amdgcn_mfma_f32_16x16x32_bf16(am[mt], bh, acc[mt][nt], 0, 0, 0);
                acc[mt][nt] = __builtin_amdgcn_mfma_f32_16x16x32_bf16(ah[mt], bm, acc[mt][nt], 0, 0, 0);
                acc[mt][nt] = __builtin_amdgcn_mfma_f32_16x16x32_bf16(al[mt], bh, acc[mt][nt], 0, 0, 0);
                acc[mt][nt] = __builtin_amdgcn_mfma_f32_16x16x32_bf16(am[mt], bm, acc[mt][nt], 0, 0, 0);
                acc[mt][nt] = __builtin_amdgcn_mfma_f32_16x16x32_bf16(ah[mt], bl, acc[mt][nt], 0, 0, 0);
            }
        }
    }

    #pragma unroll
    for (int nt = 0; nt < NT; ++nt) {
        const int col = n0 + nt * 16 + ln;
        const float bv = bias[col];
        #pragma unroll
        for (int mt = 0; mt < MT; ++mt) {
            #pragma unroll
            for (int r = 0; r < 4; ++r) {
                const int row = m0 + mt * 16 + grp * 4 + r;
                float v = acc[mt][nt][r] + bv;
                if (ACT == 1) v = v / (1.0f + expf(-v));
                if (CSWZ) C[swz(row, col, N)] = v;
                else      C[(size_t)row * N + col] = v;
                if (OUT2) {
                    unsigned short h, l;
                    split2(v, h, l);
                    const size_t o = swz(row, col, N);
                    Rh[o] = h;
                    Rl[o] = l;
                }
            }
        }
    }
}

// ---------------------------------------------------------------------------
// Split-precision MFMA GEMM (decoder): A,W as swizzled bf16 hi/lo planes;
// dot = hh + lh + hl (~2^-17 rel, only affects recon/loss, ~2% tolerance).
// Geometry templated (BM=64*MT, BN=16*NT). ACT: 1=silu, 2=sigmoid.
// OUT: 0=swizzled bf16 hi/lo pair, 1=linear single bf16.
// ---------------------------------------------------------------------------
template<int N, int K, int ACT, int OUT, int MT, int NT>
__global__ __launch_bounds__(256)
void mfma_gemm_kernel(const unsigned short* __restrict__ A_hi,
                      const unsigned short* __restrict__ A_lo,
                      const unsigned short* __restrict__ W_hi,
                      const unsigned short* __restrict__ W_lo,
                      const float* __restrict__ bias,
                      unsigned short* __restrict__ C_hi,
                      unsigned short* __restrict__ C_lo)
{
    const int tid  = threadIdx.x;
    const int lane = tid & 63;
    const int w    = tid >> 6;
    const int ln   = lane & 15;
    const int grp  = lane >> 4;
    const int m0   = blockIdx.y * (64 * MT) + w * (16 * MT);
    const int n0   = blockIdx.x * (16 * NT);

    f32x4 acc[MT][NT] = {};

    for (int ks = 0; ks < K; ks += 32) {
        const int s = ks >> 5;
        bf16x8 ah[MT], al[MT];
        #pragma unroll
        for (int mt = 0; mt < MT; ++mt) {
            const size_t off =
                ((size_t)(((m0 >> 4) + mt) * (K >> 5) + s) << 9) + lane * 8;
            ah[mt] = *(const bf16x8*)&A_hi[off];
            al[mt] = *(const bf16x8*)&A_lo[off];
        }
        #pragma unroll
        for (int nt = 0; nt < NT; ++nt) {
            const size_t off =
                ((size_t)(((n0 >> 4) + nt) * (K >> 5) + s) << 9) + lane * 8;
            bf16x8 bh = *(const bf16x8*)&W_hi[off];
            bf16x8 bl = *(const bf16x8*)&W_lo[off];
            #pragma unroll
            for (int mt = 0; mt < MT; ++mt) {
                acc[mt][nt] = __builtin_amdgcn_mfma_f32_16x16x32_bf16(ah[mt], bh, acc[mt][nt], 0, 0, 0);
                acc[mt][nt] = __builtin_amdgcn_mfma_f32_16x16x32_bf16(al[mt], bh, acc[mt][nt], 0, 0, 0);
                acc[mt][nt] = __builtin_amdgcn_mfma_f32_16x16x32_bf16(ah[mt], bl, acc[mt][nt], 0, 0, 0);
            }
        }
    }

    #pragma unroll
    for (int nt = 0; nt < NT; ++nt) {
        const int col = n0 + nt * 16 + ln;
        const float bv = bias[col];
        #pragma unroll
        for (int mt = 0; mt < MT; ++mt) {
            #pragma unroll
            for (int r = 0; r < 4; ++r) {
                const int row = m0 + mt * 16 + grp * 4 + r;
                float v = acc[mt][nt][r] + bv;
                if (ACT == 1) v = v / (1.0f + expf(-v));
                if (ACT == 2) v = 1.0f / (1.0f + expf(-v));
                if (OUT == 0) {
                    unsigned short h, l;
                    split2(v, h, l);
                    const size_t o = swz(row, col, N);
                    C_hi[o] = h;
                    C_lo[o] = l;
                } else {
                    C_hi[(size_t)row * N + col] = bf16_rne(v);
                }
            }
        }
    }
}

// ---------------------------------------------------------------------------
// Per-row L2 normalize + recon partial.
// ---------------------------------------------------------------------------
__global__ __launch_bounds__(256)
void norm_recon_kernel(const unsigned short* __restrict__ xhat,
                       const float* __restrict__ x,
                       float* __restrict__ recon_row)
{
    const int b = blockIdx.x;
    const int tid = threadIdx.x;
    __shared__ float ws[4];
    __shared__ float nrm_s;

    float v[3];
    float ss = 0.0f;
    #pragma unroll
    for (int c = 0; c < 3; ++c) {
        unsigned short u = xhat[(size_t)b * 768 + tid + c * 256];
        v[c] = __uint_as_float((unsigned)u << 16);
        ss += v[c] * v[c];
    }
    for (int off = 32; off > 0; off >>= 1) ss += __shfl_down(ss, off, 64);
    if ((tid & 63) == 0) ws[tid >> 6] = ss;
    __syncthreads();
    if (tid == 0) nrm_s = fmaxf(sqrtf(ws[0] + ws[1] + ws[2] + ws[3]), 1e-12f);
    __syncthreads();
    const float inv = 1.0f / nrm_s;
    float ra = 0.0f;
    #pragma unroll
    for (int c = 0; c < 3; ++c) {
        float dx = v[c] * inv - x[(size_t)b * 768 + tid + c * 256];
        ra += dx * dx;
    }
    for (int off = 32; off > 0; off >>= 1) ra += __shfl_down(ra, off, 64);
    if ((tid & 63) == 0) ws[tid >> 6] = ra;
    __syncthreads();
    if (tid == 0) recon_row[b] = ws[0] + ws[1] + ws[2] + ws[3];
}

// ---------------------------------------------------------------------------
// Projected codebook: cbp fp32 linear + swizzled bf16 hi/lo planes + norms.
// ---------------------------------------------------------------------------
__global__ __launch_bounds__(128)
void proj_split_kernel(const float* __restrict__ cbl, const float* __restrict__ projl,
                       float* __restrict__ cbp, unsigned short* __restrict__ cbp_hi,
                       unsigned short* __restrict__ cbp_lo, float* __restrict__ cbn)
{
    __shared__ float cbs[8][128];
    __shared__ float wsum[8][2];
    const int tid = threadIdx.x;          // = d
    const int k0 = blockIdx.x * 8;

    #pragma unroll
    for (int i = 0; i < 2; ++i) {
        int idx4 = tid + i * 128;
        int r = idx4 >> 5, c4 = (idx4 & 31) * 4;
        *(float4*)&cbs[r][c4] = *(const float4*)&cbl[(size_t)(k0 + r) * 128 + c4];
    }
    __syncthreads();

    float acc[8] = {};
    for (int j4 = 0; j4 < 32; ++j4) {
        float4 pv = *(const float4*)&projl[(size_t)tid * 128 + j4 * 4];
        #pragma unroll
        for (int r = 0; r < 8; ++r) {
            float4 cv = *(float4*)&cbs[r][j4 * 4];
            acc[r] += pv.x * cv.x + pv.y * cv.y + pv.z * cv.z + pv.w * cv.w;
        }
    }
    #pragma unroll
    for (int r = 0; r < 8; ++r) {
        cbp[(size_t)(k0 + r) * 128 + tid] = acc[r];
        unsigned short h, l;
        split2(acc[r], h, l);
        const size_t o = swz(k0 + r, tid, 128);
        cbp_hi[o] = h;
        cbp_lo[o] = l;
        float v = acc[r] * acc[r];
        #pragma unroll
        for (int off = 32; off > 0; off >>= 1) v += __shfl_down(v, off, 64);
        if ((tid & 63) == 0) wsum[r][tid >> 6] = v;
    }
    __syncthreads();
    if (tid < 8) cbn[k0 + tid] = wsum[tid][0] + wsum[tid][1];
}

// ---------------------------------------------------------------------------
// MFMA distance argmin (swizzled planes; ids bit-identical to numpy).
// BM=256 (4 m-tiles/wave), 32-col tiles x 8 its, double-buffered 2x16KB LDS
// staged via global_load_lds. launch_bounds MUST stay (256,2): the kernel
// needs ~220 VGPRs; (256,4) caps the allocator at 128 and spills A-fragments
// to scratch (r14: 454 MB FETCH/dispatch, 3x slowdown).
// ---------------------------------------------------------------------------
__device__ __forceinline__ unsigned int fkey(float s) {
    unsigned int u = __float_as_uint(s);
    return (u & 0x80000000u) ? ~u : (u | 0x80000000u);
}

__global__ __launch_bounds__(256, 2)
void argmin_mfma_kernel(const unsigned short* __restrict__ res_hi,
                        const unsigned short* __restrict__ res_lo,
                        const unsigned short* __restrict__ cbp_hi,
                        const unsigned short* __restrict__ cbp_lo,
                        const float* __restrict__ cbn,
                        unsigned long long* __restrict__ minkey)
{
    __shared__ unsigned short lds[16384];   // 2 buffers x 16 KB
    const int tid  = threadIdx.x;
    const int lane = tid & 63;
    const int w    = tid >> 6;
    const int ln   = lane & 15;
    const int grp  = lane >> 4;
    const int m0   = blockIdx.y * 256 + w * 64;
    const int c0b  = blockIdx.x * 256;

    // A fragments: 64 rows/wave (4 m-tiles), held in registers (~128 VGPR)
    bf16x8 a_hi[4][4], a_lo[4][4];
    #pragma unroll
    for (int mt = 0; mt < 4; ++mt) {
        #pragma unroll
        for (int s = 0; s < 4; ++s) {
            const size_t off =
                ((size_t)(((m0 >> 4) + mt) * 4 + s) << 9) + lane * 8;
            a_hi[mt][s] = *(const bf16x8*)&res_hi[off];
            a_lo[mt][s] = *(const bf16x8*)&res_lo[off];
        }
    }

    // Per it: B tile = 32 cols x 128 k x 2 planes = 16 KB = 16 frags of 1KB.
    const unsigned short* splane = (w < 2) ? cbp_hi : cbp_lo;
    const unsigned lbase = (unsigned)((w >> 1) * 8192 + (w & 1) * 4096); // bytes

    auto STAGE = [&](int buf, int it) {
        const size_t g0 = ((size_t)(c0b >> 4) * 4 + it * 8 + (w & 1) * 4) * 512
                        + lane * 8;                           // shorts
        const unsigned l0 = (unsigned)buf * 16384u + lbase;   // bytes
        #pragma unroll
        for (int i = 0; i < 4; ++i) {
            __builtin_amdgcn_global_load_lds(
                (const __attribute__((address_space(1))) unsigned int*)(splane + g0 + i * 512),
                (__attribute__((address_space(3))) unsigned int*)((char*)lds + l0 + i * 1024),
                16, 0, 0);
        }
    };

    float best_s[4][4];
    int   best_c[4][4];
    #pragma unroll
    for (int mt = 0; mt < 4; ++mt)
        #pragma unroll
        for (int r = 0; r < 4; ++r) { best_s[mt][r] = 3.4e38f; best_c[mt][r] = 0; }

    STAGE(0, 0);
    __syncthreads();                        // drains vmcnt -> buf0 ready

    for (int it = 0; it < 8; ++it) {
        const int buf = it & 1;
        if (it < 7) STAGE(buf ^ 1, it + 1); // async prefetch into other buffer
        const unsigned short* lb = lds + buf * 8192;   // shorts
        const int c0 = c0b + it * 32;
        f32x4 acc[4][2] = {};
        #pragma unroll
        for (int s = 0; s < 4; ++s) {
            #pragma unroll
            for (int t = 0; t < 2; ++t) {
                const int fo = (t * 4 + s) * 512 + lane * 8;
                bf16x8 bh = *(const bf16x8*)&lb[fo];
                bf16x8 bl = *(const bf16x8*)&lb[fo + 4096];
                #pragma unroll
                for (int mt = 0; mt < 4; ++mt) {
                    acc[mt][t] = __builtin_amdgcn_mfma_f32_16x16x32_bf16(a_hi[mt][s], bh, acc[mt][t], 0, 0, 0);
                    acc[mt][t] = __builtin_amdgcn_mfma_f32_16x16x32_bf16(a_lo[mt][s], bh, acc[mt][t], 0, 0, 0);
                    acc[mt][t] = __builtin_amdgcn_mfma_f32_16x16x32_bf16(a_hi[mt][s], bl, acc[mt][t], 0, 0, 0);
                }
            }
        }
        #pragma unroll
        for (int t = 0; t < 2; ++t) {
            const int col = c0 + t * 16 + ln;
            const float cn = cbn[col];
            #pragma unroll
            for (int mt = 0; mt < 4; ++mt)
                #pragma unroll
                for (int r = 0; r < 4; ++r) {
                    float sc = fmaf(-2.0f, acc[mt][t][r], cn);
                    if (sc < best_s[mt][r]) {   // strict <: first col wins ties
                        best_s[mt][r] = sc;
                        best_c[mt][r] = col;
                    }
                }
        }
        if (it < 7) __syncthreads();        // next buf ready, cur buf free
    }

    #pragma unroll
    for (int mt = 0; mt < 4; ++mt)
        #pragma unroll
        for (int r = 0; r < 4; ++r) {
            unsigned long long b =
                ((unsigned long long)fkey(best_s[mt][r]) << 32)
                | (unsigned int)best_c[mt][r];
            #pragma unroll
            for (int off = 1; off < 16; off <<= 1) {
                unsigned lo32 = (unsigned)b, hi32 = (unsigned)(b >> 32);
                lo32 = __shfl_xor(lo32, off);
                hi32 = __shfl_xor(hi32, off);
                unsigned long long o = ((unsigned long long)hi32 << 32) | lo32;
                if (o < b) b = o;
            }
            if (ln == 0) atomicMin(&minkey[m0 + mt * 16 + grp * 4 + r], b);
        }
}

// ---------------------------------------------------------------------------
// Per-layer epilogue. layer==0 WRITES qloss/z (no memset needed); layer 2
// also emits z planes for the decoder.
// ---------------------------------------------------------------------------
__global__ __launch_bounds__(128)
void finalize_kernel(float* __restrict__ res, const float* __restrict__ cbp,
                     const unsigned long long* __restrict__ minkey,
                     float* __restrict__ qloss, float* __restrict__ z,
                     int* __restrict__ ids, float* __restrict__ embs_norm_out,
                     unsigned long long* __restrict__ keys,
                     unsigned short* __restrict__ res_hi,
                     unsigned short* __restrict__ res_lo,
                     unsigned short* __restrict__ z_hi,
                     unsigned short* __restrict__ z_lo, int layer)
{
    const int b = blockIdx.x;
    const int tid = threadIdx.x;
    const int id = (int)(minkey[b] & 0xFFFFFFFFull);
    float e = cbp[(size_t)id * 128 + tid];
    float r = res[(size_t)b * 128 + tid];
    float d = r - e;
    float v1 = d * d, v2 = e * e;
    for (int off = 32; off > 0; off >>= 1) {
        v1 += __shfl_down(v1, off, 64);
        v2 += __shfl_down(v2, off, 64);
    }
    __shared__ float ws[4];
    if ((tid & 63) == 0) { ws[(tid >> 6) * 2] = v1; ws[(tid >> 6) * 2 + 1] = v2; }
    __syncthreads();
    if (tid == 0) {
        float d2 = ws[0] + ws[2];
        float n2 = ws[1] + ws[3];
        float prev = (layer == 0) ? 0.0f : qloss[b];
        qloss[b] = prev + 1.25f * d2;           // emb_loss + 0.25*query_loss
        embs_norm_out[b * 3 + layer] = sqrtf(n2);
        ids[b * 3 + layer] = id;
        if (layer == 2) {
            keys[b] = (unsigned long long)ids[b * 3 + 0]
                    | ((unsigned long long)ids[b * 3 + 1] << 13)
                    | ((unsigned long long)id << 26);
        }
    }
    float zprev = (layer == 0) ? 0.0f : z[(size_t)b * 128 + tid];
    float nz = zprev + e;
    z[(size_t)b * 128 + tid] = nz;
    const size_t o = swz(b, tid, 128);
    if (layer == 2) {
        unsigned short zh, zl;
        split2(nz, zh, zl);
        z_hi[o] = zh;
        z_lo[o] = zl;
    }
    float nr = r - e;
    res[(size_t)b * 128 + tid] = nr;
    unsigned short h, l;
    split2(nr, h, l);
    res_hi[o] = h;
    res_lo[o] = l;
}

// ---------------------------------------------------------------------------
// Distinct-triple count: wave match-any dedup (leaders only touch the global
// table) then per-wave aggregated count. Deterministic.
// ---------------------------------------------------------------------------
__global__ __launch_bounds__(256)
void uniq_hash_kernel(const unsigned long long* __restrict__ keys,
                      unsigned long long* __restrict__ table,
                      int* __restrict__ count)
{
    const int i = blockIdx.x * 256 + threadIdx.x;
    const int lane = threadIdx.x & 63;
    const unsigned long long k = keys[i];

    // wave match-any: elect one leader lane per distinct key
    bool resolved = false, leader = false;
    while (true) {
        unsigned long long unres = __ballot(!resolved);
        if (unres == 0) break;
        const int src = (int)(__ffsll((long long)unres) - 1);
        unsigned slo = __shfl((unsigned)k, src);
        unsigned shi = __shfl((unsigned)(k >> 32), src);
        unsigned long long kk = ((unsigned long long)shi << 32) | slo;
        if (!resolved && k == kk) {
            resolved = true;
            leader = (lane == src);
        }
    }

    bool ins = false;
    if (leader) {
        unsigned h = (unsigned)((k * 0x9E3779B97F4A7C15ull) >> 50);   // 14 bits
        while (true) {
            unsigned long long old = atomicCAS(&table[h], ~0ULL, k);
            if (old == ~0ULL) { ins = true; break; }        // first insert
            if (old == k) break;                            // duplicate
            h = (h + 1) & 16383;
        }
    }
    unsigned long long m = __ballot(ins);
    if (lane == 0 && m) atomicAdd(count, (int)__popcll(m));
}

// ---------------------------------------------------------------------------
// Final scalars.
// ---------------------------------------------------------------------------
__global__ __launch_bounds__(256)
void scalars_kernel(const float* __restrict__ qloss,
                    const float* __restrict__ recon_row,
                    const int* __restrict__ count, float* __restrict__ out)
{
    const int tid = threadIdx.x;
    float qs = 0.0f, rs = 0.0f;
    for (int i = tid; i < 8192; i += 256) qs += qloss[i];
    for (int i = tid; i < 8192; i += 256) rs += recon_row[i];
    for (int off = 32; off > 0; off >>= 1) {
        qs += __shfl_down(qs, off, 64);
        rs += __shfl_down(rs, off, 64);
    }
    __shared__ float w[8];
    if ((tid & 63) == 0) { w[(tid >> 6) * 2] = qs; w[(tid >> 6) * 2 + 1] = rs; }
    __syncthreads();
    if (tid == 0) {
        float qsum = w[0] + w[2] + w[4] + w[6];
        float rsum = w[1] + w[3] + w[5] + w[7];
        float qmean = qsum / 8192.0f;
        out[0] = rsum + qmean;        // loss = (recon + qloss).mean()
        out[1] = rsum;                // recon
        out[2] = qmean;               // qloss.mean()
        out[24579] = (float)(*count) / 8192.0f;   // p_unique
    }
}

// ---------------------------------------------------------------------------
extern "C" void kernel_launch(void* const* d_in, const int* in_sizes, int n_in,
                              void* d_out, int out_size, void* d_ws, size_t ws_size,
                              hipStream_t stream)
{
    const float* x      = (const float*)d_in[0];
    const float* enc_w1 = (const float*)d_in[1];
    const float* enc_b1 = (const float*)d_in[2];
    const float* enc_w2 = (const float*)d_in[3];
    const float* enc_b2 = (const float*)d_in[4];
    const float* enc_w3 = (const float*)d_in[5];
    const float* enc_b3 = (const float*)d_in[6];
    const float* dec_w1 = (const float*)d_in[7];
    const float* dec_b1 = (const float*)d_in[8];
    const float* dec_w2 = (const float*)d_in[9];
    const float* dec_b2 = (const float*)d_in[10];
    const float* dec_w3 = (const float*)d_in[11];
    const float* dec_b3 = (const float*)d_in[12];
    const float* codebooks = (const float*)d_in[13];
    const float* projs     = (const float*)d_in[14];
    float* out = (float*)d_out;

    char* ws = (char*)d_ws;
    const size_t MB = 1024 * 1024;

    // --- region [0, 16M): encoder h1 f32 (swz) ; decoder g2_hi/g2_lo (swz)
    float* h1 = (float*)ws;                                        // 8192x512 f32
    unsigned short* g2_hi = (unsigned short*)ws;                   // 8192x512 bf16
    unsigned short* g2_lo = (unsigned short*)(ws + 8 * MB);
    // --- region [16M, 24M): encoder h2 f32 (swz) ; quant splits ; dec g1 (swz)
    float* h2 = (float*)(ws + 16 * MB);                            // 8192x256 f32
    unsigned short* res_hi = (unsigned short*)(ws + 16 * MB);      // 8192x128
    unsigned short* res_lo = (unsigned short*)(ws + 18 * MB);
    unsigned short* cbp_hi = (unsigned short*)(ws + 20 * MB);
    unsigned short* cbp_lo = (unsigned short*)(ws + 22 * MB);
    unsigned short* g1_hi  = (unsigned short*)(ws + 16 * MB);      // 8192x256 (decoder)
    unsigned short* g1_lo  = (unsigned short*)(ws + 20 * MB);
    // --- region [24M, 28M): res f32 (linear)
    float* res = (float*)(ws + 24 * MB);                           // 8192x128 f32
    // --- region [28M, 32M): cbp f32 (linear) ; decoder z_hi/z_lo (swz)
    float* cbp = (float*)(ws + 28 * MB);                           // 8192x128 f32
    unsigned short* z_hi = (unsigned short*)(ws + 28 * MB);        // 8192x128
    unsigned short* z_lo = (unsigned short*)(ws + 30 * MB);
    // --- region [32M, 36M): z f32 (linear)
    float* z = (float*)(ws + 32 * MB);                             // 8192x128 f32
    // --- region [36M, ...): weight splits (all swz) + small buffers
    char* p = ws + 36 * MB;
    unsigned short* dw1_hi = (unsigned short*)p; p += 256 * 128 * 2;
    unsigned short* dw1_lo = (unsigned short*)p; p += 256 * 128 * 2;
    unsigned short* dw2_hi = (unsigned short*)p; p += 512 * 256 * 2;
    unsigned short* dw2_lo = (unsigned short*)p; p += 512 * 256 * 2;
    unsigned short* dw3_hi = (unsigned short*)p; p += 768 * 512 * 2;
    unsigned short* dw3_lo = (unsigned short*)p; p += 768 * 512 * 2;
    unsigned short* ew1_h  = (unsigned short*)p; p += 512 * 768 * 2;
    unsigned short* ew1_m  = (unsigned short*)p; p += 512 * 768 * 2;
    unsigned short* ew1_l  = (unsigned short*)p; p += 512 * 768 * 2;
    unsigned short* ew2_h  = (unsigned short*)p; p += 256 * 512 * 2;
    unsigned short* ew2_m  = (unsigned short*)p; p += 256 * 512 * 2;
    unsigned short* ew2_l  = (unsigned short*)p; p += 256 * 512 * 2;
    unsigned short* ew3_h  = (unsigned short*)p; p += 128 * 256 * 2;
    unsigned short* ew3_m  = (unsigned short*)p; p += 128 * 256 * 2;
    unsigned short* ew3_l  = (unsigned short*)p; p += 128 * 256 * 2;
    float* cbn       = (float*)p; p += 8192 * 4;
    float* qloss     = (float*)p; p += 8192 * 4;
    float* recon_row = (float*)p; p += 8192 * 4;
    unsigned long long* minkey = (unsigned long long*)p; p += 8192 * 8;
    unsigned long long* keys   = (unsigned long long*)p; p += 8192 * 8;
    unsigned long long* table  = (unsigned long long*)p; p += 16384 * 8;
    int* ids   = (int*)p; p += 8192 * 3 * 4;
    int* count = (int*)p; p += 256;                      // pad to alignment
    unsigned short* xhat = (unsigned short*)p; p += (size_t)8192 * 768 * 2;
    // optional x swizzle buffer (24 MB) — only if workspace is big enough
    float* xs = (float*)p;
    const bool use_xs =
        ((size_t)(p - ws) + (size_t)8192 * 768 * 4) <= ws_size;

    hipMemsetAsync(count, 0, sizeof(int), stream);
    hipMemsetAsync(table, 0xFF, 16384 * sizeof(unsigned long long), stream);

    // all 6 weight splits fused into one dispatch
    prep_weights_kernel<<<4352, 256, 0, stream>>>(
        dec_w1, dec_w2, dec_w3, enc_w1, enc_w2, enc_w3,
        dw1_hi, dw1_lo, dw2_hi, dw2_lo, dw3_hi, dw3_lo,
        ew1_h, ew1_m, ew1_l, ew2_h, ew2_m, ew2_l, ew3_h, ew3_m, ew3_l);

    // encoder (exact-split MFMA, fp32-faithful). Proven r10 geometry
    // throughout: MT=2/NT=4 (BM=128/BN=64).
    if (use_xs) {
        swzf32_kernel<768><<<3072, 256, 0, stream>>>(x, xs);
        mfma_enc_kernel<512, 768, 1, 1, 1, 0, 2, 4><<<dim3(8, 64), 256, 0, stream>>>(
            xs, ew1_h, ew1_m, ew1_l, enc_b1, h1, nullptr, nullptr);
    } else {
        mfma_enc_kernel<512, 768, 1, 0, 1, 0, 2, 4><<<dim3(8, 64), 256, 0, stream>>>(
            x, ew1_h, ew1_m, ew1_l, enc_b1, h1, nullptr, nullptr);
    }
    mfma_enc_kernel<256, 512, 1, 1, 1, 0, 2, 4><<<dim3(4, 64), 256, 0, stream>>>(
        h1, ew2_h, ew2_m, ew2_l, enc_b2, h2, nullptr, nullptr);
    mfma_enc_kernel<128, 256, 0, 1, 0, 1, 2, 4><<<dim3(2, 64), 256, 0, stream>>>(
        h2, ew3_h, ew3_m, ew3_l, enc_b3, res, res_hi, res_lo);

    // residual quantization layers
    for (int l = 0; l < 3; ++l) {
        proj_split_kernel<<<1024, 128, 0, stream>>>(codebooks + (size_t)l * 8192 * 128,
                                                    projs + (size_t)l * 128 * 128,
                                                    cbp, cbp_hi, cbp_lo, cbn);
        hipMemsetAsync(minkey, 0xFF, 8192 * sizeof(unsigned long long), stream);
        argmin_mfma_kernel<<<dim3(32, 32), 256, 0, stream>>>(res_hi, res_lo,
                                                             cbp_hi, cbp_lo, cbn, minkey);
        finalize_kernel<<<8192, 128, 0, stream>>>(res, cbp, minkey, qloss, z,
                                                  ids, out + 3, keys,
                                                  res_hi, res_lo, z_hi, z_lo, l);
    }

    // decoder (split-precision MFMA, swizzled planes; r10-proven geometry)
    mfma_gemm_kernel<256, 128, 1, 0, 2, 8><<<dim3(2, 64), 256, 0, stream>>>(
        z_hi, z_lo, dw1_hi, dw1_lo, dec_b1, g1_hi, g1_lo);
    mfma_gemm_kernel<512, 256, 1, 0, 2, 8><<<dim3(4, 64), 256, 0, stream>>>(
        g1_hi, g1_lo, dw2_hi, dw2_lo, dec_b2, g2_hi, g2_lo);
    mfma_gemm_kernel<768, 512, 2, 1, 2, 8><<<dim3(6, 64), 256, 0, stream>>>(
        g2_hi, g2_lo, dw3_hi, dw3_lo, dec_b3, xhat, nullptr);
    norm_recon_kernel<<<8192, 256, 0, stream>>>(xhat, x, recon_row);

    // diagnostics
    uniq_hash_kernel<<<32, 256, 0, stream>>>(keys, table, count);
    scalars_kernel<<<1, 256, 0, stream>>>(qloss, recon_row, count, out);
}